// Round 7
// baseline (849.140 us; speedup 1.0000x reference)
//
#include <hip/hip_runtime.h>
#include <math.h>

#define BB 64
#define CC 2048
#define MM 196
#define DD 256
#define NTOT (BB * MM)  // 12544

typedef __attribute__((ext_vector_type(8))) short short8;
typedef __attribute__((ext_vector_type(4))) short short4v;
typedef __attribute__((ext_vector_type(4))) unsigned short ushort4v;
typedef __attribute__((ext_vector_type(4))) float f32x4;

__device__ __forceinline__ unsigned short bf16_rne(float f) {
  unsigned int u = __float_as_uint(f);
  unsigned int r = u + 0x7FFFu + ((u >> 16) & 1u);
  return (unsigned short)(r >> 16);
}

// ---------------------------------------------------------------------------
// K0: prep — split W into bf16 hi/lo (wh+wl), precompute BN scale/shift.
// ---------------------------------------------------------------------------
__global__ __launch_bounds__(256) void k_prep(
    const float* __restrict__ w, const float* __restrict__ gamma,
    const float* __restrict__ beta, const float* __restrict__ rmean,
    const float* __restrict__ rvar, unsigned short* __restrict__ wh,
    unsigned short* __restrict__ wl, float* __restrict__ sclv,
    float* __restrict__ sftv) {
  const int e0 = (blockIdx.x * 256 + threadIdx.x) * 4;
  f32x4 v = *(const f32x4*)(w + e0);
  ushort4v h, l;
#pragma unroll
  for (int i = 0; i < 4; ++i) {
    unsigned short hb = bf16_rne(v[i]);
    float hf = __uint_as_float((unsigned int)hb << 16);
    h[i] = hb;
    l[i] = bf16_rne(v[i] - hf);
  }
  *(ushort4v*)(wh + e0) = h;
  *(ushort4v*)(wl + e0) = l;
  if (blockIdx.x == 0 && threadIdx.x < DD) {
    int d = threadIdx.x;
    float s = gamma[d] / sqrtf(rvar[d] + 1e-5f);
    sclv[d] = s;
    sftv[d] = beta[d] - rmean[d] * s;
  }
}

// ---------------------------------------------------------------------------
// K1: conv+BN+ReLU via bf16 split-3 MFMA (R6-proven, unchanged).
// ---------------------------------------------------------------------------
__global__ __launch_bounds__(256, 2) void k_conv(
    const float* __restrict__ x, const unsigned short* __restrict__ wh,
    const unsigned short* __restrict__ wl, const float* __restrict__ sclv,
    const float* __restrict__ sftv, float* __restrict__ yt) {
  const int tid = threadIdx.x;
  const int wid = tid >> 6, lane = tid & 63;
  const int quad = lane >> 4, l16 = lane & 15;
  const int n0 = blockIdx.x * 64;

  __shared__ unsigned short Xh[64][36];
  __shared__ unsigned short Xl[64][36];

  f32x4 acc[4][4];
#pragma unroll
  for (int i = 0; i < 4; ++i)
#pragma unroll
    for (int j = 0; j < 4; ++j) acc[i][j] = (f32x4)0.f;

  const int nX = tid & 63, kq = tid >> 6;
  const int gn = n0 + nX;
  const int bX = gn / MM, mX = gn - bX * MM;
  const float* xp = x + (size_t)bX * CC * MM + mX;

  float xr[8];
#pragma unroll
  for (int p = 0; p < 8; ++p) xr[p] = xp[(size_t)(kq * 8 + p) * MM];

  size_t aoff[4];
#pragma unroll
  for (int ds = 0; ds < 4; ++ds)
    aoff[ds] = (size_t)(wid * 64 + ds * 16 + l16) * CC + quad * 8;

  short8 Ah[4], Al[4], Ah2[4], Al2[4];
#pragma unroll
  for (int ds = 0; ds < 4; ++ds) {
    Ah[ds] = *(const short8*)(wh + aoff[ds]);
    Al[ds] = *(const short8*)(wl + aoff[ds]);
  }

  for (int c = 0; c < 64; ++c) {
    const int k0 = c * 32;
    __syncthreads();
    {
      ushort4v h0, h1, l0, l1;
#pragma unroll
      for (int p = 0; p < 4; ++p) {
        unsigned short hb = bf16_rne(xr[p]);
        float hf = __uint_as_float((unsigned int)hb << 16);
        h0[p] = hb;
        l0[p] = bf16_rne(xr[p] - hf);
      }
#pragma unroll
      for (int p = 0; p < 4; ++p) {
        unsigned short hb = bf16_rne(xr[4 + p]);
        float hf = __uint_as_float((unsigned int)hb << 16);
        h1[p] = hb;
        l1[p] = bf16_rne(xr[4 + p] - hf);
      }
      *(ushort4v*)&Xh[nX][kq * 8] = h0;
      *(ushort4v*)&Xh[nX][kq * 8 + 4] = h1;
      *(ushort4v*)&Xl[nX][kq * 8] = l0;
      *(ushort4v*)&Xl[nX][kq * 8 + 4] = l1;
    }
    __syncthreads();
    if (c < 63) {
#pragma unroll
      for (int p = 0; p < 8; ++p)
        xr[p] = xp[(size_t)(k0 + 32 + kq * 8 + p) * MM];
#pragma unroll
      for (int ds = 0; ds < 4; ++ds) {
        Ah2[ds] = *(const short8*)(wh + aoff[ds] + k0 + 32);
        Al2[ds] = *(const short8*)(wl + aoff[ds] + k0 + 32);
      }
    }
#pragma unroll
    for (int ns = 0; ns < 4; ++ns) {
      const unsigned short* bp = &Xh[ns * 16 + l16][quad * 8];
      short4v b0 = *(const short4v*)bp;
      short4v b1 = *(const short4v*)(bp + 4);
      short8 Bh = __builtin_shufflevector(b0, b1, 0, 1, 2, 3, 4, 5, 6, 7);
      const unsigned short* bq = &Xl[ns * 16 + l16][quad * 8];
      short4v c0 = *(const short4v*)bq;
      short4v c1 = *(const short4v*)(bq + 4);
      short8 Bl = __builtin_shufflevector(c0, c1, 0, 1, 2, 3, 4, 5, 6, 7);
#pragma unroll
      for (int ds = 0; ds < 4; ++ds) {
        acc[ds][ns] = __builtin_amdgcn_mfma_f32_16x16x32_bf16(
            Ah[ds], Bh, acc[ds][ns], 0, 0, 0);
        acc[ds][ns] = __builtin_amdgcn_mfma_f32_16x16x32_bf16(
            Ah[ds], Bl, acc[ds][ns], 0, 0, 0);
        acc[ds][ns] = __builtin_amdgcn_mfma_f32_16x16x32_bf16(
            Al[ds], Bh, acc[ds][ns], 0, 0, 0);
      }
    }
#pragma unroll
    for (int ds = 0; ds < 4; ++ds) {
      Ah[ds] = Ah2[ds];
      Al[ds] = Al2[ds];
    }
  }

#pragma unroll
  for (int ds = 0; ds < 4; ++ds) {
    const int dbase = wid * 64 + ds * 16 + quad * 4;
    f32x4 s4 = *(const f32x4*)(sclv + dbase);
    f32x4 f4 = *(const f32x4*)(sftv + dbase);
#pragma unroll
    for (int ns = 0; ns < 4; ++ns) {
      const int n = n0 + ns * 16 + l16;
      const int b = n / MM, m = n - b * MM;
      f32x4 o;
#pragma unroll
      for (int r = 0; r < 4; ++r) {
        float v = fmaf(acc[ds][ns][r], s4[r], f4[r]);
        o[r] = v > 0.f ? v : 0.f;
      }
      *(f32x4*)(yt + ((size_t)b * MM + m) * DD + dbase) = o;
    }
  }
}

// ---------------------------------------------------------------------------
// K2: per-(b,d) mean over m in fp64.
// ---------------------------------------------------------------------------
__global__ __launch_bounds__(256) void k_means(const float* __restrict__ yt,
                                               double* __restrict__ mean) {
  const int b = blockIdx.x;
  const int d = threadIdx.x;
  const float* p = yt + (size_t)b * MM * DD + d;
  double s0 = 0, s1 = 0, s2 = 0, s3 = 0;
  for (int m = 0; m < MM; m += 4) {
    s0 += (double)p[(size_t)(m + 0) * DD];
    s1 += (double)p[(size_t)(m + 1) * DD];
    s2 += (double)p[(size_t)(m + 2) * DD];
    s3 += (double)p[(size_t)(m + 3) * DD];
  }
  mean[b * DD + d] = (s0 + s1 + s2 + s3) * (1.0 / MM);
}

// ---------------------------------------------------------------------------
// K3: cov = (Y-mu)(Y-mu)^T/M + eps*I, fp64 VALU, lower tiles mirrored
// (R4/R6-proven, unchanged — mirror is required by k_chol's diag reads).
// ---------------------------------------------------------------------------
__global__ __launch_bounds__(256) void k_cov(const float* __restrict__ yt,
                                             const double* __restrict__ mean,
                                             double* __restrict__ cov) {
  const int b = blockIdx.x;
  const int t = blockIdx.y;
  const int ti = (t < 1) ? 0 : (t < 3) ? 1 : (t < 6) ? 2 : 3;
  const int tj = t - (ti * (ti + 1)) / 2;
  const int i0 = ti * 64, j0 = tj * 64;
  const int tid = threadIdx.x;
  const int tx = tid & 15, ty = tid >> 4;

  __shared__ double As[32][66];
  __shared__ double Bs[32][66];

  double acc[4][4];
#pragma unroll
  for (int i = 0; i < 4; ++i)
#pragma unroll
    for (int j = 0; j < 4; ++j) acc[i][j] = 0.0;

  const int dl = tid & 63, kl = tid >> 6;
  const double mA = mean[b * DD + i0 + dl];
  const double mB = mean[b * DD + j0 + dl];
  const float* ybase = yt + (size_t)b * MM * DD;

  for (int k0 = 0; k0 < MM; k0 += 32) {
    __syncthreads();
#pragma unroll
    for (int p = 0; p < 8; ++p) {
      int k = kl + p * 4;
      int m = k0 + k;
      double av = 0.0, bv = 0.0;
      if (m < MM) {
        av = (double)ybase[(size_t)m * DD + i0 + dl] - mA;
        bv = (double)ybase[(size_t)m * DD + j0 + dl] - mB;
      }
      As[k][dl] = av;
      Bs[k][dl] = bv;
    }
    __syncthreads();
#pragma unroll
    for (int k = 0; k < 32; ++k) {
      double a[4], bv[4];
#pragma unroll
      for (int i = 0; i < 4; ++i) a[i] = As[k][ty * 4 + i];
#pragma unroll
      for (int j = 0; j < 4; ++j) bv[j] = Bs[k][tx * 4 + j];
#pragma unroll
      for (int i = 0; i < 4; ++i)
#pragma unroll
        for (int j = 0; j < 4; ++j) acc[i][j] = fma(a[i], bv[j], acc[i][j]);
    }
  }

  double* cb = cov + (size_t)b * DD * DD;
#pragma unroll
  for (int i = 0; i < 4; ++i) {
#pragma unroll
    for (int j = 0; j < 4; ++j) {
      int gi = i0 + ty * 4 + i, gj = j0 + tx * 4 + j;
      double v = acc[i][j] * (1.0 / MM);
      if (gi == gj) v += 1e-6;
      cb[(size_t)gi * DD + gj] = v;
      if (ti != tj) cb[(size_t)gj * DD + gi] = v;
    }
  }
}

// ---------------------------------------------------------------------------
// K4: LEFT-LOOKING blocked Cholesky, ONE dispatch, one block per matrix.
// Per 32-panel kb: strip S = A[j0:,j0:j0+32] - L[j0:,0:j0]*L[j0:j0+32,0:j0]^T
// built in LDS (no global RMW anywhere); history applied in 16-wide chunks,
// double-buffered (waves 2-3 stage chunk kc+1 while threads 0-127 compute
// chunk kc into 7x8 register tiles); then shfl diag factor + register TRSM
// (proven k_panel2 code) and a single write of the L panel.
// ---------------------------------------------------------------------------
__global__ __launch_bounds__(256) void k_chol(double* __restrict__ cov) {
  const int b = blockIdx.x;
  double* A = cov + (size_t)b * DD * DD;
  const int tid = threadIdx.x;

  __shared__ double Lh[2][224][17];  // history chunk double-buffer
  __shared__ double Sp[224][33];     // current strip (kb>=1; kb=0 from global)
  __shared__ double L11s[32][33];
  __shared__ double rpivs[32];

  for (int kb = 0; kb < 8; ++kb) {
    const int j0 = kb * 32;
    const int R = DD - j0;

    if (kb > 0) {
      // Phase 1: stage strip + first history chunk (all threads, coalesced)
      for (int e = tid; e < R * 32; e += 256) {
        int r = e >> 5, c = e & 31;
        Sp[r][c] = A[(size_t)(j0 + r) * DD + j0 + c];
      }
      for (int e = tid; e < R * 16; e += 256) {
        int r = e >> 4, p = e & 15;
        Lh[0][r][p] = A[(size_t)(j0 + r) * DD + p];
      }
      __syncthreads();

      // Phase 2: register-tile update  S -= L_hist * L_hist^T
      const int rg = tid >> 2, cg = tid & 3;  // tid<128: rows rg+32i, cols 8cg+j
      const int ni = R >> 5;                  // active row-subtiles (<=7)
      const int nch = kb * 2;                 // 16-wide chunks
      double s[7][8];
#pragma unroll
      for (int i = 0; i < 7; ++i)
#pragma unroll
        for (int j = 0; j < 8; ++j) s[i][j] = 0.0;

      for (int kc = 0; kc < nch; ++kc) {
        const int cur = kc & 1;
        if (tid >= 128) {
          if (kc + 1 < nch) {
            const int koff = (kc + 1) * 16;
            for (int e = tid - 128; e < R * 16; e += 128) {
              int r = e >> 4, p = e & 15;
              Lh[cur ^ 1][r][p] = A[(size_t)(j0 + r) * DD + koff + p];
            }
          }
        } else {
#pragma unroll 4
          for (int p = 0; p < 16; ++p) {
            double bv[8];
#pragma unroll
            for (int j = 0; j < 8; ++j) bv[j] = Lh[cur][8 * cg + j][p];
#pragma unroll
            for (int i = 0; i < 7; ++i) {
              if (i < ni) {
                double av = Lh[cur][rg + 32 * i][p];
#pragma unroll
                for (int j = 0; j < 8; ++j)
                  s[i][j] = fma(av, bv[j], s[i][j]);
              }
            }
          }
        }
        __syncthreads();
      }
      if (tid < 128) {
#pragma unroll
        for (int i = 0; i < 7; ++i) {
          if (i < ni) {
#pragma unroll
            for (int j = 0; j < 8; ++j)
              Sp[rg + 32 * i][8 * cg + j] -= s[i][j];
          }
        }
      }
      __syncthreads();
    }

    // Phase 3: 32x32 diag factor in registers (lanes 0..31, zero barriers)
    if (tid < 32) {
      double r[32];
      if (kb > 0) {
#pragma unroll
        for (int k = 0; k < 32; ++k) r[k] = Sp[tid][k];
      } else {
#pragma unroll
        for (int k = 0; k < 32; ++k) r[k] = A[(size_t)(j0 + tid) * DD + j0 + k];
      }
      double rpkeep = 0.0;
#pragma unroll
      for (int j = 0; j < 32; ++j) {
        double dj = __shfl(r[j], j);
        double piv = sqrt(dj);
        double rp = 1.0 / piv;
        if (tid == j) {
          r[j] = piv;
          rpkeep = rp;
        } else {
          r[j] = r[j] * rp;  // lanes < j update junk; harmless
        }
        double lij = r[j];
#pragma unroll
        for (int k = j + 1; k < 32; ++k) {
          double ck = __shfl(lij, k);
          r[k] -= lij * ck;
        }
      }
#pragma unroll
      for (int k = 0; k < 32; ++k) L11s[tid][k] = (k <= tid) ? r[k] : 0.0;
      rpivs[tid] = rpkeep;
      for (int k = 0; k <= tid; ++k)
        A[(size_t)(j0 + tid) * DD + j0 + k] = r[k];
    }
    __syncthreads();

    // Phase 4: TRSM, thread-per-row in registers (zero barriers), write L21
    const int T = R - 32;
    if (tid < T) {
      double q[32];
      if (kb > 0) {
#pragma unroll
        for (int k = 0; k < 32; ++k) q[k] = Sp[32 + tid][k];
      } else {
#pragma unroll
        for (int k = 0; k < 32; ++k)
          q[k] = A[(size_t)(j0 + 32 + tid) * DD + j0 + k];
      }
#pragma unroll
      for (int j = 0; j < 32; ++j) {
        double sj = q[j];
#pragma unroll
        for (int k = 0; k < 32; ++k)
          if (k < j) sj -= q[k] * L11s[j][k];
        q[j] = sj * rpivs[j];
      }
      double* dst = &A[(size_t)(j0 + 32 + tid) * DD + j0];
#pragma unroll
      for (int k = 0; k < 32; ++k) dst[k] = q[k];
    }
    __syncthreads();  // L panel visible + LDS reusable before next panel
  }
}

// ---------------------------------------------------------------------------
// K5: out[b, triu(i,j)] = (i==j) ? 2*log(L[ii]) : L[j][i], fp32, coalesced.
// ---------------------------------------------------------------------------
__global__ __launch_bounds__(256) void k_out(const double* __restrict__ cov,
                                             float* __restrict__ out) {
  const int b = blockIdx.y;
  int t = blockIdx.x;
  int ti = 0, tj = t;
  while (tj >= 4 - ti) {
    tj -= (4 - ti);
    ti++;
  }
  tj += ti;
  const int tid = threadIdx.x;
  const double* A = cov + (size_t)b * DD * DD;

  __shared__ float S[64][65];
  for (int e = tid; e < 4096; e += 256) {
    int jj = e >> 6, ii = e & 63;
    S[jj][ii] = (float)A[(size_t)(tj * 64 + jj) * DD + ti * 64 + ii];
  }
  __syncthreads();

  for (int e = tid; e < 4096; e += 256) {
    int ii = e >> 6, jj = e & 63;
    int i = ti * 64 + ii, j = tj * 64 + jj;
    if (j < i) continue;
    float v = S[jj][ii];
    if (i == j) v = 2.0f * logf(v);
    int off = i * DD - (i * (i - 1)) / 2 + (j - i);
    out[(size_t)b * 32896 + off] = v;
  }
}

extern "C" void kernel_launch(void* const* d_in, const int* in_sizes, int n_in,
                              void* d_out, int out_size, void* d_ws,
                              size_t ws_size, hipStream_t stream) {
  const float* x = (const float*)d_in[0];
  const float* w = (const float*)d_in[1];
  const float* gamma = (const float*)d_in[2];
  const float* beta = (const float*)d_in[3];
  const float* rmean = (const float*)d_in[4];
  const float* rvar = (const float*)d_in[5];
  float* out = (float*)d_out;

  char* ws = (char*)d_ws;
  float* yt = (float*)ws;                           // 12,845,056 B
  double* mean = (double*)(ws + 12845056);          //    131,072 B
  double* cov = (double*)(ws + 12845056 + 131072);  // 33,554,432 B
  // alias W-prep buffers into cov (consumed by k_conv before cov is written)
  unsigned short* wh = (unsigned short*)cov;  // 1,048,576 B
  unsigned short* wl = wh + (DD * CC);        // 1,048,576 B
  float* sclv = (float*)(wl + (DD * CC));     //     1,024 B
  float* sftv = sclv + DD;                    //     1,024 B

  k_prep<<<512, 256, 0, stream>>>(w, gamma, beta, rmean, rvar, wh, wl, sclv,
                                  sftv);
  k_conv<<<NTOT / 64, 256, 0, stream>>>(x, wh, wl, sclv, sftv, yt);
  k_means<<<BB, 256, 0, stream>>>(yt, mean);
  k_cov<<<dim3(BB, 10), 256, 0, stream>>>(yt, mean, cov);
  k_chol<<<BB, 256, 0, stream>>>(cov);
  k_out<<<dim3(10, BB), 256, 0, stream>>>(cov, out);
}